// Round 5
// baseline (217.902 us; speedup 1.0000x reference)
//
#include <hip/hip_runtime.h>

// DiffeomorphicTransform: scaling-and-squaring integration of a velocity field.
//   flow = velocity / 2^7
//   repeat 7x: flow = flow + trilinear_sample(flow, sample_grid + flow_perm)
// Volume: B=1, C=3, D=H=W=128, f32.
//
// R2: AoS float4 flow -> 8 dwordx4 gathers/voxel. 92->50us/step.
// R3: separable grid -> 3x128 LDS axis tables (kernel is gather-transaction
//     bound, not BW bound).
// R4: 2x2x2 supervoxel layout: one 128B line = one 2x2x2 float4 block;
//     ~30% fewer gather line-transactions. 278->201us.
// R5: fuse init into step 1. Step-1 displacements are <=~2.7 voxels, so
//     gather straight from planar vel (L1-local) and scale each corner by
//     2^-7 (exact in f32 -> bit-identical). Deletes the ~27us init pass
//     (scattered-store bound) and its 56MB of traffic.

#define DD 128
#define HH 128
#define WW 128
#define NVOX (DD * HH * WW)          // 2,097,152
#define NELEM (3 * NVOX)             // 6,291,456
#define SCALE 63.5f                  // 0.5*(dim-1), same for x/y/z
#define INV128 (1.0f / 128.0f)

// float4-index of voxel (x,y,z) in the 2x2x2-blocked volume.
__device__ __forceinline__ int blk_addr4(int xc, int yc, int zc) {
    return ((zc >> 1) << 15) + ((yc >> 1) << 9) + ((xc >> 1) << 3)
         + ((zc & 1) << 2) + ((yc & 1) << 1) + (xc & 1);
}

// ---------------- axis-table extraction (once, 1 block) ----------------
__global__ void extract_tables_kernel(const float* __restrict__ grid,
                                      float* __restrict__ tbl) {
    int i = threadIdx.x;   // 384 threads
    if (i < 128) {
        tbl[i] = grid[3 * i + 0];                      // t_x[w]
    } else if (i < 256) {
        int h = i - 128;
        tbl[128 + h] = grid[(h * WW) * 3 + 1];         // t_y[h]
    } else if (i < 384) {
        int d = i - 256;
        tbl[256 + d] = grid[(d * HH * WW) * 3 + 2];    // t_z[d]
    }
}

// ---------------- fused step 1: flow0 = vel/128 ; out = flow0 + warp(flow0) --
// Reads vel planar (gathers are L1-local: displacement <= ~2.7 voxels),
// writes blocked AoS coalesced. Corner values scaled by 2^-7 (exact).
__global__ __launch_bounds__(256) void first_step_fused_kernel(
    const float* __restrict__ vel,     // [3][D][H][W] planar
    const float* __restrict__ tbl,     // [384] axis tables
    float4* __restrict__ dst4) {       // blocked AoS out
    __shared__ float s_tx[128], s_ty[128], s_tz[128];
    int tid = threadIdx.x;
    if (tid < 128) {
        s_tx[tid] = tbl[tid];
        s_tz[tid] = tbl[256 + tid];
    } else {
        s_ty[tid - 128] = tbl[tid];
    }
    __syncthreads();

    int gid = blockIdx.x * blockDim.x + threadIdx.x;
    if (gid >= NVOX) return;

    int phase = gid & 7;
    int sv = gid >> 3;
    int x = ((sv & 63) << 1) | (phase & 1);
    int y = (((sv >> 6) & 63) << 1) | ((phase >> 1) & 1);
    int z = ((sv >> 12) << 1) | ((phase >> 2) & 1);
    int lin = (z * HH + y) * WW + x;

    float4 f;
    f.x = vel[lin] * INV128;
    f.y = vel[NVOX + lin] * INV128;
    f.z = vel[2 * NVOX + lin] * INV128;
    f.w = 0.0f;

    float xs = (s_tx[x] + f.x + 1.0f) * SCALE;
    float ys = (s_ty[y] + f.y + 1.0f) * SCALE;
    float zs = (s_tz[z] + f.z + 1.0f) * SCALE;

    float x0f = floorf(xs), y0f = floorf(ys), z0f = floorf(zs);
    float wx = xs - x0f, wy = ys - y0f, wz = zs - z0f;
    float omx = 1.0f - wx, omy = 1.0f - wy, omz = 1.0f - wz;

    int x0 = min(max((int)x0f, 0), WW - 1);
    int x1 = min(max((int)x0f + 1, 0), WW - 1);
    int y0 = min(max((int)y0f, 0), HH - 1);
    int y1 = min(max((int)y0f + 1, 0), HH - 1);
    int z0 = min(max((int)z0f, 0), DD - 1);
    int z1 = min(max((int)z0f + 1, 0), DD - 1);

    int o00 = (z0 * HH + y0) * WW;
    int o01 = (z0 * HH + y1) * WW;
    int o10 = (z1 * HH + y0) * WW;
    int o11 = (z1 * HH + y1) * WW;

    float vx, vy, vzv;
    #pragma unroll
    for (int c = 0; c < 3; ++c) {
        const float* p = vel + c * NVOX;
        float c000 = p[o00 + x0] * INV128, c001 = p[o00 + x1] * INV128;
        float c010 = p[o01 + x0] * INV128, c011 = p[o01 + x1] * INV128;
        float c100 = p[o10 + x0] * INV128, c101 = p[o10 + x1] * INV128;
        float c110 = p[o11 + x0] * INV128, c111 = p[o11 + x1] * INV128;
        float t = (c000 * omx + c001 * wx) * omy + (c010 * omx + c011 * wx) * wy;
        float b = (c100 * omx + c101 * wx) * omy + (c110 * omx + c111 * wx) * wy;
        float v = t * omz + b * wz;
        if (c == 0) vx = v; else if (c == 1) vy = v; else vzv = v;
    }

    float4 o;
    o.x = f.x + vx;
    o.y = f.y + vy;
    o.z = f.z + vzv;
    o.w = 0.0f;
    dst4[gid] = o;                     // coalesced blocked write
}

// ---------------- warp step, blocked layout ----------------
template <bool PLANAR_OUT>
__global__ __launch_bounds__(256) void warp_step_blk_kernel(
    const float4* __restrict__ src,    // blocked AoS flow
    const float* __restrict__ tbl,     // [384] axis tables
    float4* __restrict__ dst4,         // blocked AoS out (if !PLANAR_OUT)
    float* __restrict__ dstp) {        // planar out (if PLANAR_OUT)
    __shared__ float s_tx[128], s_ty[128], s_tz[128];
    int tid = threadIdx.x;
    if (tid < 128) {
        s_tx[tid] = tbl[tid];
        s_tz[tid] = tbl[256 + tid];
    } else {
        s_ty[tid - 128] = tbl[tid];
    }
    __syncthreads();

    int gid = blockIdx.x * blockDim.x + threadIdx.x;
    if (gid >= NVOX) return;

    int phase = gid & 7;
    int sv = gid >> 3;
    int x = ((sv & 63) << 1) | (phase & 1);
    int y = (((sv >> 6) & 63) << 1) | ((phase >> 1) & 1);
    int z = ((sv >> 12) << 1) | ((phase >> 2) & 1);

    float4 f = src[gid];               // coalesced self-read

    float xs = (s_tx[x] + f.x + 1.0f) * SCALE;
    float ys = (s_ty[y] + f.y + 1.0f) * SCALE;
    float zs = (s_tz[z] + f.z + 1.0f) * SCALE;

    float x0f = floorf(xs), y0f = floorf(ys), z0f = floorf(zs);
    float wx = xs - x0f, wy = ys - y0f, wz = zs - z0f;
    float omx = 1.0f - wx, omy = 1.0f - wy, omz = 1.0f - wz;

    int x0 = min(max((int)x0f, 0), WW - 1);
    int x1 = min(max((int)x0f + 1, 0), WW - 1);
    int y0 = min(max((int)y0f, 0), HH - 1);
    int y1 = min(max((int)y0f + 1, 0), HH - 1);
    int z0 = min(max((int)z0f, 0), DD - 1);
    int z1 = min(max((int)z0f + 1, 0), DD - 1);

    float4 c000 = src[blk_addr4(x0, y0, z0)];
    float4 c001 = src[blk_addr4(x1, y0, z0)];
    float4 c010 = src[blk_addr4(x0, y1, z0)];
    float4 c011 = src[blk_addr4(x1, y1, z0)];
    float4 c100 = src[blk_addr4(x0, y0, z1)];
    float4 c101 = src[blk_addr4(x1, y0, z1)];
    float4 c110 = src[blk_addr4(x0, y1, z1)];
    float4 c111 = src[blk_addr4(x1, y1, z1)];

    float vx, vy, vzv;
    {
        float t, b;
        t = (c000.x * omx + c001.x * wx) * omy + (c010.x * omx + c011.x * wx) * wy;
        b = (c100.x * omx + c101.x * wx) * omy + (c110.x * omx + c111.x * wx) * wy;
        vx = t * omz + b * wz;
        t = (c000.y * omx + c001.y * wx) * omy + (c010.y * omx + c011.y * wx) * wy;
        b = (c100.y * omx + c101.y * wx) * omy + (c110.y * omx + c111.y * wx) * wy;
        vy = t * omz + b * wz;
        t = (c000.z * omx + c001.z * wx) * omy + (c010.z * omx + c011.z * wx) * wy;
        b = (c100.z * omx + c101.z * wx) * omy + (c110.z * omx + c111.z * wx) * wy;
        vzv = t * omz + b * wz;
    }

    if (PLANAR_OUT) {
        int lin = (z * HH + y) * WW + x;
        dstp[lin] = f.x + vx;
        dstp[NVOX + lin] = f.y + vy;
        dstp[2 * NVOX + lin] = f.z + vzv;
    } else {
        float4 o;
        o.x = f.x + vx;
        o.y = f.y + vy;
        o.z = f.z + vzv;
        o.w = 0.0f;
        dst4[gid] = o;                 // coalesced
    }
}

// ---------------- linear-AoS path (fallback, mid ws) ----------------
__global__ __launch_bounds__(256) void init_flow_aos_kernel(
    const float* __restrict__ vel, float4* __restrict__ flow) {
    int i = blockIdx.x * blockDim.x + threadIdx.x;
    if (i >= NVOX) return;
    float4 f;
    f.x = vel[i] * INV128;
    f.y = vel[NVOX + i] * INV128;
    f.z = vel[2 * NVOX + i] * INV128;
    f.w = 0.0f;
    flow[i] = f;
}

template <bool PLANAR_OUT>
__global__ __launch_bounds__(256) void warp_step_aos_kernel(
    const float4* __restrict__ src, const float* __restrict__ grid,
    float4* __restrict__ dst4, float* __restrict__ dstp) {
    int idx = blockIdx.x * blockDim.x + threadIdx.x;
    if (idx >= NVOX) return;

    float4 f = src[idx];
    float gx = grid[3 * idx + 0];
    float gy = grid[3 * idx + 1];
    float gz = grid[3 * idx + 2];

    float x = (gx + f.x + 1.0f) * SCALE;
    float y = (gy + f.y + 1.0f) * SCALE;
    float z = (gz + f.z + 1.0f) * SCALE;

    float x0f = floorf(x), y0f = floorf(y), z0f = floorf(z);
    float wx = x - x0f, wy = y - y0f, wz = z - z0f;
    float omx = 1.0f - wx, omy = 1.0f - wy, omz = 1.0f - wz;

    int x0 = min(max((int)x0f, 0), WW - 1);
    int x1 = min(max((int)x0f + 1, 0), WW - 1);
    int y0 = min(max((int)y0f, 0), HH - 1);
    int y1 = min(max((int)y0f + 1, 0), HH - 1);
    int z0 = min(max((int)z0f, 0), DD - 1);
    int z1 = min(max((int)z0f + 1, 0), DD - 1);

    const float4* r00 = src + (z0 * HH + y0) * WW;
    const float4* r01 = src + (z0 * HH + y1) * WW;
    const float4* r10 = src + (z1 * HH + y0) * WW;
    const float4* r11 = src + (z1 * HH + y1) * WW;

    float4 c000 = r00[x0], c001 = r00[x1];
    float4 c010 = r01[x0], c011 = r01[x1];
    float4 c100 = r10[x0], c101 = r10[x1];
    float4 c110 = r11[x0], c111 = r11[x1];

    float vx, vy, vzv;
    {
        float t, b;
        t = (c000.x * omx + c001.x * wx) * omy + (c010.x * omx + c011.x * wx) * wy;
        b = (c100.x * omx + c101.x * wx) * omy + (c110.x * omx + c111.x * wx) * wy;
        vx = t * omz + b * wz;
        t = (c000.y * omx + c001.y * wx) * omy + (c010.y * omx + c011.y * wx) * wy;
        b = (c100.y * omx + c101.y * wx) * omy + (c110.y * omx + c111.y * wx) * wy;
        vy = t * omz + b * wz;
        t = (c000.z * omx + c001.z * wx) * omy + (c010.z * omx + c011.z * wx) * wy;
        b = (c100.z * omx + c101.z * wx) * omy + (c110.z * omx + c111.z * wx) * wy;
        vzv = t * omz + b * wz;
    }

    if (PLANAR_OUT) {
        dstp[idx] = f.x + vx;
        dstp[NVOX + idx] = f.y + vy;
        dstp[2 * NVOX + idx] = f.z + vzv;
    } else {
        float4 o;
        o.x = f.x + vx; o.y = f.y + vy; o.z = f.z + vzv; o.w = 0.0f;
        dst4[idx] = o;
    }
}

// ---------------- planar fallback (tiny ws) ----------------
__global__ __launch_bounds__(256) void init_flow_kernel(
    const float* __restrict__ vel, float* __restrict__ flow) {
    int i = blockIdx.x * blockDim.x + threadIdx.x;
    if (i < NELEM) flow[i] = vel[i] * INV128;
}

__global__ __launch_bounds__(256) void warp_step_kernel(
    const float* __restrict__ src, const float* __restrict__ grid,
    float* __restrict__ dst) {
    int idx = blockIdx.x * blockDim.x + threadIdx.x;
    if (idx >= NVOX) return;

    float fx = src[idx];
    float fy = src[NVOX + idx];
    float fz = src[2 * NVOX + idx];
    float gx = grid[idx * 3 + 0];
    float gy = grid[idx * 3 + 1];
    float gz = grid[idx * 3 + 2];

    float x = (gx + fx + 1.0f) * SCALE;
    float y = (gy + fy + 1.0f) * SCALE;
    float z = (gz + fz + 1.0f) * SCALE;

    float x0f = floorf(x), y0f = floorf(y), z0f = floorf(z);
    float wx = x - x0f, wy = y - y0f, wz = z - z0f;

    int x0 = min(max((int)x0f, 0), WW - 1);
    int x1 = min(max((int)x0f + 1, 0), WW - 1);
    int y0 = min(max((int)y0f, 0), HH - 1);
    int y1 = min(max((int)y0f + 1, 0), HH - 1);
    int z0 = min(max((int)z0f, 0), DD - 1);
    int z1 = min(max((int)z0f + 1, 0), DD - 1);

    int o00 = (z0 * HH + y0) * WW;
    int o01 = (z0 * HH + y1) * WW;
    int o10 = (z1 * HH + y0) * WW;
    int o11 = (z1 * HH + y1) * WW;

    float omx = 1.0f - wx, omy = 1.0f - wy, omz = 1.0f - wz;

    #pragma unroll
    for (int c = 0; c < 3; ++c) {
        const float* p = src + c * NVOX;
        float c000 = p[o00 + x0], c001 = p[o00 + x1];
        float c010 = p[o01 + x0], c011 = p[o01 + x1];
        float c100 = p[o10 + x0], c101 = p[o10 + x1];
        float c110 = p[o11 + x0], c111 = p[o11 + x1];
        float top = (c000 * omx + c001 * wx) * omy + (c010 * omx + c011 * wx) * wy;
        float bot = (c100 * omx + c101 * wx) * omy + (c110 * omx + c111 * wx) * wy;
        float val = top * omz + bot * wz;
        float fcur = (c == 0) ? fx : ((c == 1) ? fy : fz);
        dst[c * NVOX + idx] = fcur + val;
    }
}

// ---------------- launch ----------------
extern "C" void kernel_launch(void* const* d_in, const int* in_sizes, int n_in,
                              void* d_out, int out_size, void* d_ws, size_t ws_size,
                              hipStream_t stream) {
    const float* vel  = (const float*)d_in[0];   // [1,3,128,128,128]
    const float* grid = (const float*)d_in[1];   // [1,128,128,128,3]
    float* out = (float*)d_out;

    const size_t aos_bytes = (size_t)NVOX * 16;  // 32 MiB per buffer
    const size_t tbl_bytes = 4096;               // 3*128 floats, padded

    if (ws_size >= 2 * aos_bytes + tbl_bytes) {
        // Fast path: tables + fused step1 + blocked ping-pong.
        float* tbl = (float*)d_ws;
        float4* A = (float4*)((char*)d_ws + tbl_bytes);
        float4* B = A + NVOX;

        extract_tables_kernel<<<1, 384, 0, stream>>>(grid, tbl);
        // Step 1 fused with init: planar vel gathers (L1-local), blocked out.
        first_step_fused_kernel<<<(NVOX + 255) / 256, 256, 0, stream>>>(vel, tbl, A);

        // Steps 2..6 blocked ping-pong: A->B->A->B->A->B
        const float4* cur = A;
        for (int it = 0; it < 5; ++it) {
            float4* nxt = (it & 1) ? A : B;
            warp_step_blk_kernel<false><<<(NVOX + 255) / 256, 256, 0, stream>>>(
                cur, tbl, nxt, nullptr);
            cur = nxt;
        }
        // Step 7 writes planar f32 straight to d_out.
        warp_step_blk_kernel<true><<<(NVOX + 255) / 256, 256, 0, stream>>>(
            cur, tbl, nullptr, out);
    } else if (ws_size >= 2 * aos_bytes) {
        // Linear AoS path with grid reads (R2).
        float4* A = (float4*)d_ws;
        float4* B = A + NVOX;
        init_flow_aos_kernel<<<(NVOX + 255) / 256, 256, 0, stream>>>(vel, A);
        const float4* cur = A;
        for (int it = 0; it < 6; ++it) {
            float4* nxt = (it & 1) ? A : B;
            warp_step_aos_kernel<false><<<(NVOX + 255) / 256, 256, 0, stream>>>(
                cur, grid, nxt, nullptr);
            cur = nxt;
        }
        warp_step_aos_kernel<true><<<(NVOX + 255) / 256, 256, 0, stream>>>(
            cur, grid, nullptr, out);
    } else {
        // Planar fallback (24 MiB ws).
        float* ws = (float*)d_ws;
        init_flow_kernel<<<(NELEM + 255) / 256, 256, 0, stream>>>(vel, ws);
        const float* cur = ws;
        for (int it = 0; it < 7; ++it) {
            float* nxt = (it & 1) ? ws : out;
            warp_step_kernel<<<(NVOX + 255) / 256, 256, 0, stream>>>(cur, grid, nxt);
            cur = nxt;
        }
    }
}

// Round 6
// 196.564 us; speedup vs baseline: 1.1086x; 1.1086x over previous
//
#include <hip/hip_runtime.h>

// DiffeomorphicTransform: scaling-and-squaring integration of a velocity field.
//   flow = velocity / 2^7
//   repeat 7x: flow = flow + trilinear_sample(flow, sample_grid + flow_perm)
// Volume: B=1, C=3, D=H=W=128, f32.
//
// R2: AoS float4 flow -> 8 dwordx4 gathers/voxel. 92->50us/step.
// R3: separable grid -> 3x128 LDS axis tables (gather-transaction bound).
// R4: 2x2x2 supervoxel layout (one 128B line per 2x2x2 block). 278->201us.
// R5: FAILED fusion of init into step1 (24 planar scalar gathers cost 60us;
//     scalar gather INSTRUCTION COUNT dominates, not displacement locality).
// R6: revert fusion; init rewritten blocked-order: coalesced blocked WRITES
//     (was 32 partial-line writes/wave), scattered planar reads (only 12x64B
//     segments/wave). Table extraction folded into init block 0.

#define DD 128
#define HH 128
#define WW 128
#define NVOX (DD * HH * WW)          // 2,097,152
#define NELEM (3 * NVOX)             // 6,291,456
#define SCALE 63.5f                  // 0.5*(dim-1), same for x/y/z
#define INV128 (1.0f / 128.0f)

// float4-index of voxel (x,y,z) in the 2x2x2-blocked volume.
__device__ __forceinline__ int blk_addr4(int xc, int yc, int zc) {
    return ((zc >> 1) << 15) + ((yc >> 1) << 9) + ((xc >> 1) << 3)
         + ((zc & 1) << 2) + ((yc & 1) << 1) + (xc & 1);
}

// ---------------- init: flow0 = vel/128, blocked-order (coalesced writes) ---
// Also extracts the 3x128 axis tables (block 0 only; bit-identical values:
// grid [D][H][W][3] is a broadcast meshgrid).
__global__ __launch_bounds__(256) void init_blk_kernel(
    const float* __restrict__ vel,     // [3][D][H][W] planar
    const float* __restrict__ grid,    // [D][H][W][3]
    float4* __restrict__ flow,         // blocked AoS out
    float* __restrict__ tbl) {         // [384] axis tables out
    if (blockIdx.x == 0) {
        int i = threadIdx.x;
        if (i < 128) {
            tbl[i]       = grid[3 * i + 0];                  // t_x[w]
            tbl[128 + i] = grid[(i * WW) * 3 + 1];           // t_y[h]
            tbl[256 + i] = grid[(i * HH * WW) * 3 + 2];      // t_z[d]
        }
    }

    int gid = blockIdx.x * blockDim.x + threadIdx.x;   // blocked index
    if (gid >= NVOX) return;

    int phase = gid & 7;
    int sv = gid >> 3;
    int x = ((sv & 63) << 1) | (phase & 1);
    int y = (((sv >> 6) & 63) << 1) | ((phase >> 1) & 1);
    int z = ((sv >> 12) << 1) | ((phase >> 2) & 1);
    int lin = (z * HH + y) * WW + x;

    float4 f;
    f.x = vel[lin] * INV128;
    f.y = vel[NVOX + lin] * INV128;
    f.z = vel[2 * NVOX + lin] * INV128;
    f.w = 0.0f;
    flow[gid] = f;                     // coalesced blocked write
}

// ---------------- warp step, blocked layout ----------------
template <bool PLANAR_OUT>
__global__ __launch_bounds__(256) void warp_step_blk_kernel(
    const float4* __restrict__ src,    // blocked AoS flow
    const float* __restrict__ tbl,     // [384] axis tables
    float4* __restrict__ dst4,         // blocked AoS out (if !PLANAR_OUT)
    float* __restrict__ dstp) {        // planar out (if PLANAR_OUT)
    __shared__ float s_tx[128], s_ty[128], s_tz[128];
    int tid = threadIdx.x;
    if (tid < 128) {
        s_tx[tid] = tbl[tid];
        s_tz[tid] = tbl[256 + tid];
    } else {
        s_ty[tid - 128] = tbl[tid];
    }
    __syncthreads();

    int gid = blockIdx.x * blockDim.x + threadIdx.x;
    if (gid >= NVOX) return;

    int phase = gid & 7;
    int sv = gid >> 3;
    int x = ((sv & 63) << 1) | (phase & 1);
    int y = (((sv >> 6) & 63) << 1) | ((phase >> 1) & 1);
    int z = ((sv >> 12) << 1) | ((phase >> 2) & 1);

    float4 f = src[gid];               // coalesced self-read

    float xs = (s_tx[x] + f.x + 1.0f) * SCALE;
    float ys = (s_ty[y] + f.y + 1.0f) * SCALE;
    float zs = (s_tz[z] + f.z + 1.0f) * SCALE;

    float x0f = floorf(xs), y0f = floorf(ys), z0f = floorf(zs);
    float wx = xs - x0f, wy = ys - y0f, wz = zs - z0f;
    float omx = 1.0f - wx, omy = 1.0f - wy, omz = 1.0f - wz;

    int x0 = min(max((int)x0f, 0), WW - 1);
    int x1 = min(max((int)x0f + 1, 0), WW - 1);
    int y0 = min(max((int)y0f, 0), HH - 1);
    int y1 = min(max((int)y0f + 1, 0), HH - 1);
    int z0 = min(max((int)z0f, 0), DD - 1);
    int z1 = min(max((int)z0f + 1, 0), DD - 1);

    float4 c000 = src[blk_addr4(x0, y0, z0)];
    float4 c001 = src[blk_addr4(x1, y0, z0)];
    float4 c010 = src[blk_addr4(x0, y1, z0)];
    float4 c011 = src[blk_addr4(x1, y1, z0)];
    float4 c100 = src[blk_addr4(x0, y0, z1)];
    float4 c101 = src[blk_addr4(x1, y0, z1)];
    float4 c110 = src[blk_addr4(x0, y1, z1)];
    float4 c111 = src[blk_addr4(x1, y1, z1)];

    float vx, vy, vzv;
    {
        float t, b;
        t = (c000.x * omx + c001.x * wx) * omy + (c010.x * omx + c011.x * wx) * wy;
        b = (c100.x * omx + c101.x * wx) * omy + (c110.x * omx + c111.x * wx) * wy;
        vx = t * omz + b * wz;
        t = (c000.y * omx + c001.y * wx) * omy + (c010.y * omx + c011.y * wx) * wy;
        b = (c100.y * omx + c101.y * wx) * omy + (c110.y * omx + c111.y * wx) * wy;
        vy = t * omz + b * wz;
        t = (c000.z * omx + c001.z * wx) * omy + (c010.z * omx + c011.z * wx) * wy;
        b = (c100.z * omx + c101.z * wx) * omy + (c110.z * omx + c111.z * wx) * wy;
        vzv = t * omz + b * wz;
    }

    if (PLANAR_OUT) {
        int lin = (z * HH + y) * WW + x;
        dstp[lin] = f.x + vx;
        dstp[NVOX + lin] = f.y + vy;
        dstp[2 * NVOX + lin] = f.z + vzv;
    } else {
        float4 o;
        o.x = f.x + vx;
        o.y = f.y + vy;
        o.z = f.z + vzv;
        o.w = 0.0f;
        dst4[gid] = o;                 // coalesced
    }
}

// ---------------- linear-AoS path (fallback, mid ws) ----------------
__global__ __launch_bounds__(256) void init_flow_aos_kernel(
    const float* __restrict__ vel, float4* __restrict__ flow) {
    int i = blockIdx.x * blockDim.x + threadIdx.x;
    if (i >= NVOX) return;
    float4 f;
    f.x = vel[i] * INV128;
    f.y = vel[NVOX + i] * INV128;
    f.z = vel[2 * NVOX + i] * INV128;
    f.w = 0.0f;
    flow[i] = f;
}

template <bool PLANAR_OUT>
__global__ __launch_bounds__(256) void warp_step_aos_kernel(
    const float4* __restrict__ src, const float* __restrict__ grid,
    float4* __restrict__ dst4, float* __restrict__ dstp) {
    int idx = blockIdx.x * blockDim.x + threadIdx.x;
    if (idx >= NVOX) return;

    float4 f = src[idx];
    float gx = grid[3 * idx + 0];
    float gy = grid[3 * idx + 1];
    float gz = grid[3 * idx + 2];

    float x = (gx + f.x + 1.0f) * SCALE;
    float y = (gy + f.y + 1.0f) * SCALE;
    float z = (gz + f.z + 1.0f) * SCALE;

    float x0f = floorf(x), y0f = floorf(y), z0f = floorf(z);
    float wx = x - x0f, wy = y - y0f, wz = z - z0f;
    float omx = 1.0f - wx, omy = 1.0f - wy, omz = 1.0f - wz;

    int x0 = min(max((int)x0f, 0), WW - 1);
    int x1 = min(max((int)x0f + 1, 0), WW - 1);
    int y0 = min(max((int)y0f, 0), HH - 1);
    int y1 = min(max((int)y0f + 1, 0), HH - 1);
    int z0 = min(max((int)z0f, 0), DD - 1);
    int z1 = min(max((int)z0f + 1, 0), DD - 1);

    const float4* r00 = src + (z0 * HH + y0) * WW;
    const float4* r01 = src + (z0 * HH + y1) * WW;
    const float4* r10 = src + (z1 * HH + y0) * WW;
    const float4* r11 = src + (z1 * HH + y1) * WW;

    float4 c000 = r00[x0], c001 = r00[x1];
    float4 c010 = r01[x0], c011 = r01[x1];
    float4 c100 = r10[x0], c101 = r10[x1];
    float4 c110 = r11[x0], c111 = r11[x1];

    float vx, vy, vzv;
    {
        float t, b;
        t = (c000.x * omx + c001.x * wx) * omy + (c010.x * omx + c011.x * wx) * wy;
        b = (c100.x * omx + c101.x * wx) * omy + (c110.x * omx + c111.x * wx) * wy;
        vx = t * omz + b * wz;
        t = (c000.y * omx + c001.y * wx) * omy + (c010.y * omx + c011.y * wx) * wy;
        b = (c100.y * omx + c101.y * wx) * omy + (c110.y * omx + c111.y * wx) * wy;
        vy = t * omz + b * wz;
        t = (c000.z * omx + c001.z * wx) * omy + (c010.z * omx + c011.z * wx) * wy;
        b = (c100.z * omx + c101.z * wx) * omy + (c110.z * omx + c111.z * wx) * wy;
        vzv = t * omz + b * wz;
    }

    if (PLANAR_OUT) {
        dstp[idx] = f.x + vx;
        dstp[NVOX + idx] = f.y + vy;
        dstp[2 * NVOX + idx] = f.z + vzv;
    } else {
        float4 o;
        o.x = f.x + vx; o.y = f.y + vy; o.z = f.z + vzv; o.w = 0.0f;
        dst4[idx] = o;
    }
}

// ---------------- planar fallback (tiny ws) ----------------
__global__ __launch_bounds__(256) void init_flow_kernel(
    const float* __restrict__ vel, float* __restrict__ flow) {
    int i = blockIdx.x * blockDim.x + threadIdx.x;
    if (i < NELEM) flow[i] = vel[i] * INV128;
}

__global__ __launch_bounds__(256) void warp_step_kernel(
    const float* __restrict__ src, const float* __restrict__ grid,
    float* __restrict__ dst) {
    int idx = blockIdx.x * blockDim.x + threadIdx.x;
    if (idx >= NVOX) return;

    float fx = src[idx];
    float fy = src[NVOX + idx];
    float fz = src[2 * NVOX + idx];
    float gx = grid[idx * 3 + 0];
    float gy = grid[idx * 3 + 1];
    float gz = grid[idx * 3 + 2];

    float x = (gx + fx + 1.0f) * SCALE;
    float y = (gy + fy + 1.0f) * SCALE;
    float z = (gz + fz + 1.0f) * SCALE;

    float x0f = floorf(x), y0f = floorf(y), z0f = floorf(z);
    float wx = x - x0f, wy = y - y0f, wz = z - z0f;

    int x0 = min(max((int)x0f, 0), WW - 1);
    int x1 = min(max((int)x0f + 1, 0), WW - 1);
    int y0 = min(max((int)y0f, 0), HH - 1);
    int y1 = min(max((int)y0f + 1, 0), HH - 1);
    int z0 = min(max((int)z0f, 0), DD - 1);
    int z1 = min(max((int)z0f + 1, 0), DD - 1);

    int o00 = (z0 * HH + y0) * WW;
    int o01 = (z0 * HH + y1) * WW;
    int o10 = (z1 * HH + y0) * WW;
    int o11 = (z1 * HH + y1) * WW;

    float omx = 1.0f - wx, omy = 1.0f - wy, omz = 1.0f - wz;

    #pragma unroll
    for (int c = 0; c < 3; ++c) {
        const float* p = src + c * NVOX;
        float c000 = p[o00 + x0], c001 = p[o00 + x1];
        float c010 = p[o01 + x0], c011 = p[o01 + x1];
        float c100 = p[o10 + x0], c101 = p[o10 + x1];
        float c110 = p[o11 + x0], c111 = p[o11 + x1];
        float top = (c000 * omx + c001 * wx) * omy + (c010 * omx + c011 * wx) * wy;
        float bot = (c100 * omx + c101 * wx) * omy + (c110 * omx + c111 * wx) * wy;
        float val = top * omz + bot * wz;
        float fcur = (c == 0) ? fx : ((c == 1) ? fy : fz);
        dst[c * NVOX + idx] = fcur + val;
    }
}

// ---------------- launch ----------------
extern "C" void kernel_launch(void* const* d_in, const int* in_sizes, int n_in,
                              void* d_out, int out_size, void* d_ws, size_t ws_size,
                              hipStream_t stream) {
    const float* vel  = (const float*)d_in[0];   // [1,3,128,128,128]
    const float* grid = (const float*)d_in[1];   // [1,128,128,128,3]
    float* out = (float*)d_out;

    const size_t aos_bytes = (size_t)NVOX * 16;  // 32 MiB per buffer
    const size_t tbl_bytes = 4096;               // 3*128 floats, padded

    if (ws_size >= 2 * aos_bytes + tbl_bytes) {
        // Fast path: blocked-order init (tables folded in) + blocked ping-pong.
        float* tbl = (float*)d_ws;
        float4* A = (float4*)((char*)d_ws + tbl_bytes);
        float4* B = A + NVOX;

        init_blk_kernel<<<(NVOX + 255) / 256, 256, 0, stream>>>(vel, grid, A, tbl);

        // Steps 1..6 blocked ping-pong: A->B->A->B->A->B->A
        const float4* cur = A;
        for (int it = 0; it < 6; ++it) {
            float4* nxt = (it & 1) ? A : B;
            warp_step_blk_kernel<false><<<(NVOX + 255) / 256, 256, 0, stream>>>(
                cur, tbl, nxt, nullptr);
            cur = nxt;
        }
        // Step 7 writes planar f32 straight to d_out.
        warp_step_blk_kernel<true><<<(NVOX + 255) / 256, 256, 0, stream>>>(
            cur, tbl, nullptr, out);
    } else if (ws_size >= 2 * aos_bytes) {
        // Linear AoS path with grid reads (R2).
        float4* A = (float4*)d_ws;
        float4* B = A + NVOX;
        init_flow_aos_kernel<<<(NVOX + 255) / 256, 256, 0, stream>>>(vel, A);
        const float4* cur = A;
        for (int it = 0; it < 6; ++it) {
            float4* nxt = (it & 1) ? A : B;
            warp_step_aos_kernel<false><<<(NVOX + 255) / 256, 256, 0, stream>>>(
                cur, grid, nxt, nullptr);
            cur = nxt;
        }
        warp_step_aos_kernel<true><<<(NVOX + 255) / 256, 256, 0, stream>>>(
            cur, grid, nullptr, out);
    } else {
        // Planar fallback (24 MiB ws).
        float* ws = (float*)d_ws;
        init_flow_kernel<<<(NELEM + 255) / 256, 256, 0, stream>>>(vel, ws);
        const float* cur = ws;
        for (int it = 0; it < 7; ++it) {
            float* nxt = (it & 1) ? ws : out;
            warp_step_kernel<<<(NVOX + 255) / 256, 256, 0, stream>>>(cur, grid, nxt);
            cur = nxt;
        }
    }
}